// Round 10
// baseline (50.358 us; speedup 1.0000x reference)
//
#include <hip/hip_runtime.h>

// Problem constants (match reference)
#define NB 32768
#define ND 512
#define NK 10

#define LEFTB (-10.0f)
#define RIGHTB (10.0f)
#define ROWS 8
#define BX 576      // grid = (576, 4) = 2304 blocks = exactly 9 blocks/CU (LDS capacity)
#define FPB 128     // features per block

// DPP row_shr:N add (VALU-only partial reduction within 16-lane rows).
__device__ __forceinline__ float dpp_row_reduce16(float v) {
    // after the 4 adds, lane (15 mod 16) holds the sum of its 16-lane row
    v += __int_as_float(__builtin_amdgcn_update_dpp(
        0, __float_as_int(v), 0x111, 0xF, 0xF, true));  // row_shr:1
    v += __int_as_float(__builtin_amdgcn_update_dpp(
        0, __float_as_int(v), 0x112, 0xF, 0xF, true));  // row_shr:2
    v += __int_as_float(__builtin_amdgcn_update_dpp(
        0, __float_as_int(v), 0x114, 0xF, 0xF, true));  // row_shr:4
    v += __int_as_float(__builtin_amdgcn_update_dpp(
        0, __float_as_int(v), 0x118, 0xF, 0xF, true));  // row_shr:8
    return v;
}

// ---------------------------------------------------------------------------
// Fused kernel. Prologue: each thread computes its OWN feature's spline
// tables (softmax -> knots, softplus derivatives) and writes them to its own
// LDS column — LDS serves as per-thread dynamically-indexable storage
// (sCWCH[idx][t] is only ever read by thread t). Main loop is round-9's
// proven inner loop: 0 bank conflicts, pure-VALU DPP reduce, log2 units.
// ---------------------------------------------------------------------------
__global__ __launch_bounds__(128) void rqs_fused(const float* __restrict__ X,
                                                 const float* __restrict__ uw,
                                                 const float* __restrict__ uh,
                                                 const float* __restrict__ ud,
                                                 float* __restrict__ Y,
                                                 float* __restrict__ part) {
    const int t = threadIdx.x;
    const int q = blockIdx.y;        // feature quarter 0..3
    const int f = q * FPB + t;

    __shared__ float2 sCWCH[NK + 1][FPB];  // 11264 B
    __shared__ float sDD[NK + 1][FPB];     //  5632 B  (16.9 KB total)

    // ---- per-feature table build (was a separate kernel) ----
    float cw[NK + 1], ch[NK + 1];
    {
        float u[NK];
        float m = -1e30f;
#pragma unroll
        for (int k = 0; k < NK; ++k) { u[k] = uw[f * NK + k]; m = fmaxf(m, u[k]); }
        float s = 0.0f;
#pragma unroll
        for (int k = 0; k < NK; ++k) { u[k] = expf(u[k] - m); s += u[k]; }
        float inv = 1.0f / s;
        float c = 0.0f;
        cw[0] = LEFTB;
#pragma unroll
        for (int k = 0; k < NK; ++k) {
            c += 1e-3f + (1.0f - 1e-3f * NK) * (u[k] * inv);
            cw[k + 1] = (RIGHTB - LEFTB) * c + LEFTB;
        }
        cw[NK] = RIGHTB;
    }
    {
        float u[NK];
        float m = -1e30f;
#pragma unroll
        for (int k = 0; k < NK; ++k) { u[k] = uh[f * NK + k]; m = fmaxf(m, u[k]); }
        float s = 0.0f;
#pragma unroll
        for (int k = 0; k < NK; ++k) { u[k] = expf(u[k] - m); s += u[k]; }
        float inv = 1.0f / s;
        float c = 0.0f;
        ch[0] = LEFTB;
#pragma unroll
        for (int k = 0; k < NK; ++k) {
            c += 1e-3f + (1.0f - 1e-3f * NK) * (u[k] * inv);
            ch[k + 1] = (RIGHTB - LEFTB) * c + LEFTB;
        }
        ch[NK] = RIGHTB;
    }
    // derivatives: boundary pads are exactly 1.0
    sDD[0][t] = 1.0f;
    sDD[NK][t] = 1.0f;
#pragma unroll
    for (int k = 1; k < NK; ++k) {
        float v = ud[f * (NK - 1) + (k - 1)];
        sDD[k][t] = 1e-3f + fmaxf(v, 0.0f) + log1pf(expf(-fabsf(v)));
    }
#pragma unroll
    for (int k = 0; k <= NK; ++k) sCWCH[k][t] = make_float2(cw[k], ch[k]);

    float e[9];
#pragma unroll
    for (int j = 0; j < 9; ++j) e[j] = cw[j + 1];
    __syncthreads();

    // ---- main loop (round-9 inner loop, unchanged) ----
    const int step = gridDim.x * ROWS;

    for (int r0 = blockIdx.x * ROWS; r0 < NB; r0 += step) {
        float xs[ROWS], ys[ROWS], ls[ROWS];
#pragma unroll
        for (int i = 0; i < ROWS; ++i)
            xs[i] = __builtin_nontemporal_load(&X[(r0 + i) * ND + f]);

#pragma unroll
        for (int i = 0; i < ROWS; ++i) {
            float x = xs[i];

            // bin search on raw x: saturates to 0 / 9 outside, same as clamp
            int idx = 0;
#pragma unroll
            for (int j = 0; j < 9; ++j) idx += (x >= e[j]) ? 1 : 0;

            float2 c0 = sCWCH[idx][t];      // {cw_k,   ch_k}
            float2 c1 = sCWCH[idx + 1][t];  // {cw_k+1, ch_k+1}
            float dk = sDD[idx][t];
            float dk1 = sDD[idx + 1][t];

            float w = c1.x - c0.x;
            float rw = __builtin_amdgcn_rcpf(w);   // w >= 0.02 always
            float h = c1.y - c0.y;
            float delta = h * rw;

            float theta = (x - c0.x) * rw;
            float omt = 1.0f - theta;
            float t1m = theta * omt;
            float th2 = theta * theta;

            float num = h * fmaf(delta, th2, dk * t1m);
            float den = fmaf(fmaf(-2.0f, delta, dk + dk1), t1m, delta);
            float rden = __builtin_amdgcn_rcpf(den);  // den > 0 inside
            float y = fmaf(num, rden, c0.y);

            float dnum = delta * delta *
                         (fmaf(dk1, th2, 2.0f * delta * t1m) + dk * omt * omt);
            float lad2 = __log2f(dnum * rden * rden);  // log2; ln2 applied later

            bool inside = fabsf(x) <= RIGHTB;          // abs = free src modifier
            ys[i] = inside ? y : x;
            ls[i] = inside ? lad2 : 0.0f;
        }

#pragma unroll
        for (int i = 0; i < ROWS; ++i)
            __builtin_nontemporal_store(ys[i], &Y[(r0 + i) * ND + f]);

        // pure-VALU DPP reduce within 16-lane rows; lane 15 holds the sum
#pragma unroll
        for (int i = 0; i < ROWS; ++i) ls[i] = dpp_row_reduce16(ls[i]);
        if ((t & 15) == 15) {
            int g = q * 8 + (t >> 4);  // 0..31 across the four quarters
#pragma unroll
            for (int i = 0; i < ROWS; ++i) part[(r0 + i) * 32 + g] = ls[i];
        }
    }
}

// ---------------------------------------------------------------------------
// logdet = ln2 * sum of 32 log2-partials per row. 8 threads per row, float4.
// ---------------------------------------------------------------------------
__global__ __launch_bounds__(256) void rqs_reduce(const float* __restrict__ part,
                                                  float* __restrict__ logdet) {
    int j = blockIdx.x * 256 + threadIdx.x;
    int row = j >> 3;
    int sub = j & 7;
    float4 v = ((const float4*)part)[row * 8 + sub];
    float s = (v.x + v.y) + (v.z + v.w);
    s += __shfl_xor(s, 1, 64);
    s += __shfl_xor(s, 2, 64);
    s += __shfl_xor(s, 4, 64);
    if (sub == 0) logdet[row] = s * 0.6931471805599453f;
}

extern "C" void kernel_launch(void* const* d_in, const int* in_sizes, int n_in,
                              void* d_out, int out_size, void* d_ws, size_t ws_size,
                              hipStream_t stream) {
    const float* x  = (const float*)d_in[0];
    const float* uw = (const float*)d_in[1];
    const float* uh = (const float*)d_in[2];
    const float* ud = (const float*)d_in[3];

    float* out = (float*)d_out;
    float* Y = out;                              // [NB*ND]
    float* logdet = out + (size_t)NB * ND;       // [NB]

    float* part = (float*)d_ws;                  // NB*32 floats (4 MB)

    hipLaunchKernelGGL(rqs_fused, dim3(BX, 4), dim3(FPB), 0, stream,
                       x, uw, uh, ud, Y, part);
    hipLaunchKernelGGL(rqs_reduce, dim3(NB * 8 / 256), dim3(256), 0, stream,
                       part, logdet);
}

// Round 11
// 43.060 us; speedup vs baseline: 1.1695x; 1.1695x over previous
//
#include <hip/hip_runtime.h>

// Problem constants (match reference)
#define NB 32768
#define ND 512
#define NK 10

#define LEFTB (-10.0f)
#define RIGHTB (10.0f)
#define ROWS 8
#define NBLK 512    // blocks; 512 threads each; 2 blocks/CU (LDS-limited)

// ---------------------------------------------------------------------------
// Workspace layout (floats):
//   E     [ 9][512]          internal knots cw[1..9] (register bin search)
//   GCWCH [11][512] float2   {cw_k, ch_k} knot pairs
//   GDD   [11][512]          d_k
// ---------------------------------------------------------------------------
#define OFF_CWCH (9 * ND)                   // floats
#define OFF_DD   (OFF_CWCH + 22 * ND)       // floats

__global__ void rqs_precompute(const float* __restrict__ uw,
                               const float* __restrict__ uh,
                               const float* __restrict__ ud,
                               float* __restrict__ ws) {
    int f = blockIdx.x * blockDim.x + threadIdx.x;
    if (f >= ND) return;

    float* E = ws;
    float2* GCWCH = (float2*)(ws + OFF_CWCH);
    float* GDD = ws + OFF_DD;

    float cw[NK + 1], ch[NK + 1], dd[NK + 1];

    // ---- widths -> x-knots ----
    {
        float u[NK];
        float m = -1e30f;
#pragma unroll
        for (int k = 0; k < NK; ++k) { u[k] = uw[f * NK + k]; m = fmaxf(m, u[k]); }
        float s = 0.0f;
#pragma unroll
        for (int k = 0; k < NK; ++k) { u[k] = expf(u[k] - m); s += u[k]; }
        float inv = 1.0f / s;
        float c = 0.0f;
        cw[0] = LEFTB;
#pragma unroll
        for (int k = 0; k < NK; ++k) {
            c += 1e-3f + (1.0f - 1e-3f * NK) * (u[k] * inv);
            cw[k + 1] = (RIGHTB - LEFTB) * c + LEFTB;
        }
        cw[NK] = RIGHTB;
    }
    // ---- heights -> y-knots ----
    {
        float u[NK];
        float m = -1e30f;
#pragma unroll
        for (int k = 0; k < NK; ++k) { u[k] = uh[f * NK + k]; m = fmaxf(m, u[k]); }
        float s = 0.0f;
#pragma unroll
        for (int k = 0; k < NK; ++k) { u[k] = expf(u[k] - m); s += u[k]; }
        float inv = 1.0f / s;
        float c = 0.0f;
        ch[0] = LEFTB;
#pragma unroll
        for (int k = 0; k < NK; ++k) {
            c += 1e-3f + (1.0f - 1e-3f * NK) * (u[k] * inv);
            ch[k + 1] = (RIGHTB - LEFTB) * c + LEFTB;
        }
        ch[NK] = RIGHTB;
    }
    // ---- derivatives: boundary pads are exactly 1.0 ----
    dd[0] = 1.0f;
    dd[NK] = 1.0f;
#pragma unroll
    for (int k = 1; k < NK; ++k) {
        float v = ud[f * (NK - 1) + (k - 1)];
        dd[k] = 1e-3f + fmaxf(v, 0.0f) + log1pf(expf(-fabsf(v)));
    }

    // ---- store ----
#pragma unroll
    for (int j = 0; j < 9; ++j) E[j * ND + f] = cw[j + 1];
#pragma unroll
    for (int k = 0; k <= NK; ++k) {
        GCWCH[k * ND + f] = make_float2(cw[k], ch[k]);
        GDD[k * ND + f] = dd[k];
    }
}

// DPP row_shr:N add (VALU-only partial reduction within 16-lane rows).
__device__ __forceinline__ float dpp_row_reduce16(float v) {
    v += __int_as_float(__builtin_amdgcn_update_dpp(
        0, __float_as_int(v), 0x111, 0xF, 0xF, true));  // row_shr:1
    v += __int_as_float(__builtin_amdgcn_update_dpp(
        0, __float_as_int(v), 0x112, 0xF, 0xF, true));  // row_shr:2
    v += __int_as_float(__builtin_amdgcn_update_dpp(
        0, __float_as_int(v), 0x114, 0xF, 0xF, true));  // row_shr:4
    v += __int_as_float(__builtin_amdgcn_update_dpp(
        0, __float_as_int(v), 0x118, 0xF, 0xF, true));  // row_shr:8
    return v;
}

// ---------------------------------------------------------------------------
// Main transform. Block = 512 threads = ALL features -> block owns complete
// rows, so logdet is finished in-kernel (no part buffer, no reduce kernel).
// LDS [knot][512] planes: stride 4096/2048 B (== 0 mod 32 banks) -> per-lane
// idx gather conflict-free (r6/r9-verified layout). Inner element code is
// round-9's proven version (DPP reduce, log2 units, no clamp).
// ---------------------------------------------------------------------------
__global__ __launch_bounds__(512) void rqs_main(const float* __restrict__ X,
                                                const float* __restrict__ ws,
                                                float* __restrict__ Y,
                                                float* __restrict__ logdet) {
    const int t = threadIdx.x;  // feature index

    __shared__ float2 sCWCH[NK + 1][ND];  // 45056 B
    __shared__ float sDD[NK + 1][ND];     // 22528 B
    __shared__ float sPart[ROWS][32];     //  1024 B   (68.6 KB total -> 2 blk/CU)

    const float* E = ws;
    const float2* GCWCH = (const float2*)(ws + OFF_CWCH);
    const float* GDD = ws + OFF_DD;

#pragma unroll
    for (int k = 0; k <= NK; ++k) {
        sCWCH[k][t] = GCWCH[k * ND + t];
        sDD[k][t] = GDD[k * ND + t];
    }
    float e[9];
#pragma unroll
    for (int j = 0; j < 9; ++j) e[j] = E[j * ND + t];
    __syncthreads();

    // 512 blocks x ROWS rows x 8 iterations covers NB exactly; iteration
    // count is uniform across blocks -> barriers are safe.
    for (int r0 = blockIdx.x * ROWS; r0 < NB; r0 += NBLK * ROWS) {
        float xs[ROWS], ys[ROWS], ls[ROWS];
#pragma unroll
        for (int i = 0; i < ROWS; ++i)
            xs[i] = __builtin_nontemporal_load(&X[(r0 + i) * ND + t]);

#pragma unroll
        for (int i = 0; i < ROWS; ++i) {
            float x = xs[i];

            // bin search on raw x: saturates to 0 / 9 outside, same as clamp
            int idx = 0;
#pragma unroll
            for (int j = 0; j < 9; ++j) idx += (x >= e[j]) ? 1 : 0;

            float2 c0 = sCWCH[idx][t];      // {cw_k,   ch_k}
            float2 c1 = sCWCH[idx + 1][t];  // {cw_k+1, ch_k+1}
            float dk = sDD[idx][t];
            float dk1 = sDD[idx + 1][t];

            float w = c1.x - c0.x;
            float rw = __builtin_amdgcn_rcpf(w);   // w >= 0.02 always
            float h = c1.y - c0.y;
            float delta = h * rw;

            float theta = (x - c0.x) * rw;
            float omt = 1.0f - theta;
            float t1m = theta * omt;
            float th2 = theta * theta;

            float num = h * fmaf(delta, th2, dk * t1m);
            float den = fmaf(fmaf(-2.0f, delta, dk + dk1), t1m, delta);
            float rden = __builtin_amdgcn_rcpf(den);  // den > 0 inside
            float y = fmaf(num, rden, c0.y);

            float dnum = delta * delta *
                         (fmaf(dk1, th2, 2.0f * delta * t1m) + dk * omt * omt);
            float lad2 = __log2f(dnum * rden * rden);  // log2; ln2 applied at end

            bool inside = fabsf(x) <= RIGHTB;          // abs = free src modifier
            ys[i] = inside ? y : x;
            ls[i] = inside ? lad2 : 0.0f;
        }

#pragma unroll
        for (int i = 0; i < ROWS; ++i)
            __builtin_nontemporal_store(ys[i], &Y[(r0 + i) * ND + t]);

        // pure-VALU DPP reduce within 16-lane groups; lane 15 holds group sum
#pragma unroll
        for (int i = 0; i < ROWS; ++i) ls[i] = dpp_row_reduce16(ls[i]);
        if ((t & 15) == 15) {
            int g = t >> 4;  // 0..31
#pragma unroll
            for (int i = 0; i < ROWS; ++i) sPart[i][g] = ls[i];
        }
        __syncthreads();

        // finish: 256 threads sum 32 partials per row (rows don't straddle
        // 32-lane halves), write logdet directly
        if (t < 256) {
            float v = ((const float*)sPart)[t];  // row = t>>5, group = t&31
            v += __shfl_xor(v, 1, 32);
            v += __shfl_xor(v, 2, 32);
            v += __shfl_xor(v, 4, 32);
            v += __shfl_xor(v, 8, 32);
            v += __shfl_xor(v, 16, 32);
            if ((t & 31) == 0)
                logdet[r0 + (t >> 5)] = v * 0.6931471805599453f;
        }
        __syncthreads();  // protect sPart before next iteration overwrites
    }
}

extern "C" void kernel_launch(void* const* d_in, const int* in_sizes, int n_in,
                              void* d_out, int out_size, void* d_ws, size_t ws_size,
                              hipStream_t stream) {
    const float* x  = (const float*)d_in[0];
    const float* uw = (const float*)d_in[1];
    const float* uh = (const float*)d_in[2];
    const float* ud = (const float*)d_in[3];

    float* out = (float*)d_out;
    float* Y = out;                              // [NB*ND]
    float* logdet = out + (size_t)NB * ND;       // [NB]

    float* ws = (float*)d_ws;                    // tables: 53*512 floats (~106 KB)

    hipLaunchKernelGGL(rqs_precompute, dim3(4), dim3(128), 0, stream,
                       uw, uh, ud, ws);
    hipLaunchKernelGGL(rqs_main, dim3(NBLK), dim3(ND), 0, stream,
                       x, ws, Y, logdet);
}

// Round 12
// 42.186 us; speedup vs baseline: 1.1937x; 1.0207x over previous
//
#include <hip/hip_runtime.h>

// Problem constants (match reference)
#define NB 32768
#define ND 512
#define NK 10

#define LEFTB (-10.0f)
#define RIGHTB (10.0f)
#define ROWS 8
#define NBLK 512    // 512 threads each; 2 blocks/CU (LDS-limited); 8 sweeps
#define SWEEPS (NB / (NBLK * ROWS))   // = 8

// ---------------------------------------------------------------------------
// Workspace layout (floats):
//   E     [ 9][512]          internal knots cw[1..9] (register bin search)
//   GCWCH [11][512] float2   {cw_k, ch_k} knot pairs
//   GDD   [11][512]          d_k
// ---------------------------------------------------------------------------
#define OFF_CWCH (9 * ND)                   // floats
#define OFF_DD   (OFF_CWCH + 22 * ND)       // floats

__global__ void rqs_precompute(const float* __restrict__ uw,
                               const float* __restrict__ uh,
                               const float* __restrict__ ud,
                               float* __restrict__ ws) {
    int f = blockIdx.x * blockDim.x + threadIdx.x;
    if (f >= ND) return;

    float* E = ws;
    float2* GCWCH = (float2*)(ws + OFF_CWCH);
    float* GDD = ws + OFF_DD;

    float cw[NK + 1], ch[NK + 1], dd[NK + 1];

    // ---- widths -> x-knots ----
    {
        float u[NK];
        float m = -1e30f;
#pragma unroll
        for (int k = 0; k < NK; ++k) { u[k] = uw[f * NK + k]; m = fmaxf(m, u[k]); }
        float s = 0.0f;
#pragma unroll
        for (int k = 0; k < NK; ++k) { u[k] = expf(u[k] - m); s += u[k]; }
        float inv = 1.0f / s;
        float c = 0.0f;
        cw[0] = LEFTB;
#pragma unroll
        for (int k = 0; k < NK; ++k) {
            c += 1e-3f + (1.0f - 1e-3f * NK) * (u[k] * inv);
            cw[k + 1] = (RIGHTB - LEFTB) * c + LEFTB;
        }
        cw[NK] = RIGHTB;
    }
    // ---- heights -> y-knots ----
    {
        float u[NK];
        float m = -1e30f;
#pragma unroll
        for (int k = 0; k < NK; ++k) { u[k] = uh[f * NK + k]; m = fmaxf(m, u[k]); }
        float s = 0.0f;
#pragma unroll
        for (int k = 0; k < NK; ++k) { u[k] = expf(u[k] - m); s += u[k]; }
        float inv = 1.0f / s;
        float c = 0.0f;
        ch[0] = LEFTB;
#pragma unroll
        for (int k = 0; k < NK; ++k) {
            c += 1e-3f + (1.0f - 1e-3f * NK) * (u[k] * inv);
            ch[k + 1] = (RIGHTB - LEFTB) * c + LEFTB;
        }
        ch[NK] = RIGHTB;
    }
    // ---- derivatives: boundary pads are exactly 1.0 ----
    dd[0] = 1.0f;
    dd[NK] = 1.0f;
#pragma unroll
    for (int k = 1; k < NK; ++k) {
        float v = ud[f * (NK - 1) + (k - 1)];
        dd[k] = 1e-3f + fmaxf(v, 0.0f) + log1pf(expf(-fabsf(v)));
    }

    // ---- store ----
#pragma unroll
    for (int j = 0; j < 9; ++j) E[j * ND + f] = cw[j + 1];
#pragma unroll
    for (int k = 0; k <= NK; ++k) {
        GCWCH[k * ND + f] = make_float2(cw[k], ch[k]);
        GDD[k * ND + f] = dd[k];
    }
}

// DPP row_shr:N add (VALU-only partial reduction within 16-lane rows).
__device__ __forceinline__ float dpp_row_reduce16(float v) {
    v += __int_as_float(__builtin_amdgcn_update_dpp(
        0, __float_as_int(v), 0x111, 0xF, 0xF, true));  // row_shr:1
    v += __int_as_float(__builtin_amdgcn_update_dpp(
        0, __float_as_int(v), 0x112, 0xF, 0xF, true));  // row_shr:2
    v += __int_as_float(__builtin_amdgcn_update_dpp(
        0, __float_as_int(v), 0x114, 0xF, 0xF, true));  // row_shr:4
    v += __int_as_float(__builtin_amdgcn_update_dpp(
        0, __float_as_int(v), 0x118, 0xF, 0xF, true));  // row_shr:8
    return v;
}

// ---------------------------------------------------------------------------
// Main transform. Block = 512 threads = ALL features. Loop is barrier-free:
// per-sweep logdet partials land in a private LDS slab (distinct region per
// sweep), finished once in an epilogue after a single barrier. Next sweep's
// X batch is prefetched during compute (VGPR headroom is free: LDS is the
// occupancy binder at 2 blocks/CU). Per-element code = round-9 proven.
// ---------------------------------------------------------------------------
__global__ __launch_bounds__(512) void rqs_main(const float* __restrict__ X,
                                                const float* __restrict__ ws,
                                                float* __restrict__ Y,
                                                float* __restrict__ logdet) {
    const int t = threadIdx.x;  // feature index

    __shared__ float2 sCWCH[NK + 1][ND];            // 45056 B
    __shared__ float sDD[NK + 1][ND];               // 22528 B
    __shared__ float sPart[SWEEPS * ROWS][32] __attribute__((aligned(16)));  // 8192 B
    // total 75776 B -> 2 blocks/CU

    const float* E = ws;
    const float2* GCWCH = (const float2*)(ws + OFF_CWCH);
    const float* GDD = ws + OFF_DD;

#pragma unroll
    for (int k = 0; k <= NK; ++k) {
        sCWCH[k][t] = GCWCH[k * ND + t];
        sDD[k][t] = GDD[k * ND + t];
    }
    float e[9];
#pragma unroll
    for (int j = 0; j < 9; ++j) e[j] = E[j * ND + t];
    __syncthreads();

    // prologue: load sweep 0
    float xs[ROWS];
    {
        const int rb = blockIdx.x * ROWS;
#pragma unroll
        for (int i = 0; i < ROWS; ++i)
            xs[i] = __builtin_nontemporal_load(&X[(rb + i) * ND + t]);
    }

    for (int it = 0; it < SWEEPS; ++it) {
        const int rb = blockIdx.x * ROWS + it * (NBLK * ROWS);

        // prefetch next sweep's X during this sweep's compute
        float xn[ROWS];
        if (it + 1 < SWEEPS) {
            const int rn = rb + NBLK * ROWS;
#pragma unroll
            for (int i = 0; i < ROWS; ++i)
                xn[i] = __builtin_nontemporal_load(&X[(rn + i) * ND + t]);
        }

        float ys[ROWS], ls[ROWS];
#pragma unroll
        for (int i = 0; i < ROWS; ++i) {
            float x = xs[i];

            // bin search on raw x: saturates to 0 / 9 outside, same as clamp
            int idx = 0;
#pragma unroll
            for (int j = 0; j < 9; ++j) idx += (x >= e[j]) ? 1 : 0;

            float2 c0 = sCWCH[idx][t];      // {cw_k,   ch_k}
            float2 c1 = sCWCH[idx + 1][t];  // {cw_k+1, ch_k+1}
            float dk = sDD[idx][t];
            float dk1 = sDD[idx + 1][t];

            float w = c1.x - c0.x;
            float rw = __builtin_amdgcn_rcpf(w);   // w >= 0.02 always
            float h = c1.y - c0.y;
            float delta = h * rw;

            float theta = (x - c0.x) * rw;
            float omt = 1.0f - theta;
            float t1m = theta * omt;
            float th2 = theta * theta;

            float num = h * fmaf(delta, th2, dk * t1m);
            float den = fmaf(fmaf(-2.0f, delta, dk + dk1), t1m, delta);
            float rden = __builtin_amdgcn_rcpf(den);  // den > 0 inside
            float y = fmaf(num, rden, c0.y);

            float dnum = delta * delta *
                         (fmaf(dk1, th2, 2.0f * delta * t1m) + dk * omt * omt);
            float lad2 = __log2f(dnum * rden * rden);  // log2; ln2 applied at end

            bool inside = fabsf(x) <= RIGHTB;          // abs = free src modifier
            ys[i] = inside ? y : x;
            ls[i] = inside ? lad2 : 0.0f;
        }

#pragma unroll
        for (int i = 0; i < ROWS; ++i)
            __builtin_nontemporal_store(ys[i], &Y[(rb + i) * ND + t]);

        // pure-VALU DPP reduce within 16-lane groups; lane 15 holds group sum
#pragma unroll
        for (int i = 0; i < ROWS; ++i) ls[i] = dpp_row_reduce16(ls[i]);
        if ((t & 15) == 15) {
            int g = t >> 4;  // 0..31
#pragma unroll
            for (int i = 0; i < ROWS; ++i) sPart[it * ROWS + i][g] = ls[i];
        }
        // no barrier: each sweep writes a distinct sPart region

#pragma unroll
        for (int i = 0; i < ROWS; ++i) xs[i] = xn[i];
    }

    // ---- epilogue: finish all 64 rows' logdet in one pass ----
    __syncthreads();
    {
        const int rl = t >> 3;              // local row 0..63
        const int c = t & 7;                // 8 threads per row
        const int it = rl >> 3;
        const int i = rl & 7;
        float4 v4 = *(const float4*)&sPart[rl][c * 4];
        float v = (v4.x + v4.y) + (v4.z + v4.w);
        v += __shfl_xor(v, 1, 8);
        v += __shfl_xor(v, 2, 8);
        v += __shfl_xor(v, 4, 8);
        if (c == 0) {
            const int row = blockIdx.x * ROWS + it * (NBLK * ROWS) + i;
            logdet[row] = v * 0.6931471805599453f;
        }
    }
}

extern "C" void kernel_launch(void* const* d_in, const int* in_sizes, int n_in,
                              void* d_out, int out_size, void* d_ws, size_t ws_size,
                              hipStream_t stream) {
    const float* x  = (const float*)d_in[0];
    const float* uw = (const float*)d_in[1];
    const float* uh = (const float*)d_in[2];
    const float* ud = (const float*)d_in[3];

    float* out = (float*)d_out;
    float* Y = out;                              // [NB*ND]
    float* logdet = out + (size_t)NB * ND;       // [NB]

    float* ws = (float*)d_ws;                    // tables: 53*512 floats (~106 KB)

    hipLaunchKernelGGL(rqs_precompute, dim3(4), dim3(128), 0, stream,
                       uw, uh, ud, ws);
    hipLaunchKernelGGL(rqs_main, dim3(NBLK), dim3(ND), 0, stream,
                       x, ws, Y, logdet);
}